// Round 2
// baseline (1055.060 us; speedup 1.0000x reference)
//
#include <hip/hip_runtime.h>

#define B_ 1024
#define T_ 366
#define NS_ 365
#define CD_ 24
#define NTASK (B_ * NS_)

__device__ __forceinline__ float sigm(float x) {
    return __fdividef(1.f, 1.f + __expf(-x));
}

// ---------------- Phase 1: recurrence, 4 waves (256 thr) per batch element ----------------
// Roles: all threads: redis rows {tid, tid+256} (register weights)
//        wave1 (tid 64..127):  redis row 512+(tid-64), weights re-read from global (L1)
//        wave2 (tid 128..176): part/cons/assim row (global weights) + in-wave Cmid
//        wave0 lanes 0..23:    redis row softmax + scale
//        wave3 lanes 0..23:    einsum column sums, C write-back
__global__ __launch_bounds__(256, 4) void mclstm_phase1(
    const float* __restrict__ X, const float* __restrict__ ORY,
    const float* __restrict__ Wr, const float* __restrict__ br,
    const float* __restrict__ Wp, const float* __restrict__ bp,
    const float* __restrict__ Wc, const float* __restrict__ bc,
    const float* __restrict__ Wa, const float* __restrict__ ba,
    float* __restrict__ Ccell)
{
    const int b = blockIdx.x;
    const int tid = threadIdx.x;

    __shared__ alignas(16) float zbuf[CD_ * 25];  // 24 rows stride 25
    __shared__ alignas(16) float cbuf[CD_];
    __shared__ float cmid[CD_];

    // register weights: rows tid and tid+256, masked cols {0..23, 25->rad}
    float wA[25], wB[25], bA, bB;
    {
        const float* wa = Wr + (size_t)tid * 29;
        const float* wb = Wr + (size_t)(tid + 256) * 29;
#pragma unroll
        for (int k = 0; k < 24; ++k) { wA[k] = wa[k]; wB[k] = wb[k]; }
        wA[24] = wa[25]; wB[24] = wb[25];
        bA = br[tid]; bB = br[tid + 256];
    }
    const int zaA = (tid / 24) * 25 + (tid % 24);
    const int zaB = ((tid + 256) / 24) * 25 + ((tid + 256) % 24);

    // third-row pointer (wave1) — weights stay in L1 (13KB shared per CU)
    const float* wcp = nullptr; float bC = 0.f; int zaC = 0;
    if (tid >= 64 && tid < 128) {
        const int e = 512 + (tid - 64);
        wcp = Wr + (size_t)e * 29;
        bC = br[e];
        zaC = (e / 24) * 25 + (e % 24);
    }

    // part/cons/assim row pointer (wave2)
    const int l2 = tid - 128;                 // lane within wave2
    const float* wxp = nullptr; float bx = 0.f;
    if (l2 >= 0 && l2 < 49) {
        if (l2 < 24)      { wxp = Wp + (size_t)l2 * 29;        bx = bp[l2]; }
        else if (l2 < 48) { wxp = Wc + (size_t)(l2 - 24) * 29; bx = bc[l2 - 24]; }
        else              { wxp = Wa;                          bx = ba[0]; }
    }

    if (tid < CD_) cbuf[tid] = 0.f;
    __syncthreads();

    float Ncum = 0.f;
    const float* xrow = X + (size_t)b * T_ * 4;
    const float* orow = ORY + (size_t)b * T_ * 7;

    for (int t = 0; t < NS_; ++t) {
        const float rad = xrow[t * 4 + 0];
        const float tmx = xrow[t * 4 + 1];
        const float tmn = xrow[t * 4 + 2];
        Ncum += xrow[t * 4 + 3];
        const float dvs = orow[t * 7];

        const float tave = 0.5f * (tmx + tmn);
        const float cl = fminf(fmaxf(tave * 50.f, 10.f), 40.f);
        const float eff = 0.54f - (cl - 10.f) * (0.18f / 30.f);
        const float cpot = rad * (eff * (2.f * 0.5f / 3.6f * (12.f / 44.f)));

        // current C (uniform broadcast reads)
        float Cg[24];
#pragma unroll
        for (int q = 0; q < 6; ++q) {
            const float4 v = ((const float4*)cbuf)[q];
            Cg[4 * q + 0] = v.x; Cg[4 * q + 1] = v.y;
            Cg[4 * q + 2] = v.z; Cg[4 * q + 3] = v.w;
        }

        // --- dot products ---
        {
            float zA = bA, zB = bB;
#pragma unroll
            for (int k = 0; k < 24; ++k) {
                zA = fmaf(wA[k], Cg[k], zA);
                zB = fmaf(wB[k], Cg[k], zB);
            }
            zA = fmaf(wA[24], rad, zA);
            zB = fmaf(wB[24], rad, zB);
            zbuf[zaA] = zA;
            zbuf[zaB] = zB;
        }
        if (wcp) {
            float zC = bC;
#pragma unroll
            for (int k = 0; k < 24; ++k) zC = fmaf(wcp[k], Cg[k], zC);
            zC = fmaf(wcp[25], rad, zC);
            zbuf[zaC] = zC;
        }
        // --- wave2: part/cons/assim + Cmid, fully in-wave ---
        if (l2 >= 0 && l2 < 49) {
            float pz = bx;
#pragma unroll
            for (int k = 0; k < 24; ++k) pz = fmaf(wxp[k], Cg[k], pz);
            pz = fmaf(wxp[24], dvs, pz);
            pz = fmaf(wxp[25], rad, pz);
            pz = fmaf(wxp[26], tmx, pz);
            pz = fmaf(wxp[27], tmn, pz);
            pz = fmaf(wxp[28], Ncum, pz);

            float pm = (l2 < 24) ? pz : -1e30f;
#pragma unroll
            for (int o = 1; o < 32; o <<= 1) pm = fmaxf(pm, __shfl_xor(pm, o, 32));
            float pe = (l2 < 24) ? __expf(pz - pm) : 0.f;
            float ps = pe;
#pragma unroll
            for (int o = 1; o < 32; o <<= 1) ps += __shfl_xor(ps, o, 32);

            // pull cons-z (lanes 24..47) and assim-z (lane 48); all source lanes active
            const float conz = __shfl(pz, (l2 < 24) ? (24 + l2) : 24, 64);
            const float asmz = __shfl(pz, 48, 64);
            if (l2 < 24) {
                const float part  = __fdividef(pe, ps);
                const float cons  = sigm(conz);
                const float assim = sigm(asmz);
                const float vCr = cbuf[l2];
                cmid[l2] = (vCr + assim * cpot * part) * (1.f - cons);
            }
        }
        __syncthreads();                       // B1: zbuf + cmid ready

        // --- wave0: row softmax + scale in place ---
        if (tid < 24) {
            float zr[24];
#pragma unroll
            for (int c = 0; c < 24; ++c) zr[c] = zbuf[tid * 25 + c];
            float m2 = zr[0];
#pragma unroll
            for (int c = 1; c < 24; ++c) m2 = fmaxf(m2, zr[c]);
            float ss = 0.f;
#pragma unroll
            for (int c = 0; c < 24; ++c) { zr[c] = __expf(zr[c] - m2); ss += zr[c]; }
            const float fac = __fdividef(cmid[tid], ss);
#pragma unroll
            for (int c = 0; c < 24; ++c) zbuf[tid * 25 + c] = zr[c] * fac;
        }
        __syncthreads();                       // B2: scaled P ready

        // --- wave3: column sums -> new C ---
        if (tid >= 192 && tid < 192 + 24) {
            const int c = tid - 192;
            float Cn = 0.f;
#pragma unroll
            for (int r = 0; r < 24; ++r) Cn += zbuf[r * 25 + c];
            cbuf[c] = Cn;
            Ccell[((size_t)b * NS_ + t) * CD_ + c] = Cn;
        }
        __syncthreads();                       // B3: C(t+1) visible
    }
}

// ---------------- Phase 2: C_conv + all_day, one (b,t) task per lane ----------------
__global__ __launch_bounds__(256, 4) void mclstm_phase2(
    const float* __restrict__ X, const float* __restrict__ ORY,
    const float* __restrict__ Wr, const float* __restrict__ br,
    const float* __restrict__ c2a, const float* __restrict__ g2y,
    const float* __restrict__ Ccell, float* __restrict__ allday,
    float* __restrict__ Cconv)
{
    const int tid = blockIdx.x * 256 + threadIdx.x;

    // all_day[:,0,:] = ORY[:,0,:7]
    if (tid < B_) {
#pragma unroll
        for (int k = 0; k < 7; ++k)
            allday[(size_t)tid * T_ * 7 + k] = ORY[(size_t)tid * T_ * 7 + k];
    }
    if (tid >= NTASK) return;
    const int b = tid / NS_;
    const int t = tid - b * NS_;

    const float* Cp = Ccell + (size_t)tid * CD_;
    float C[24];
#pragma unroll
    for (int q = 0; q < 6; ++q) {
        const float4 v = *(const float4*)(Cp + 4 * q);
        C[4 * q + 0] = v.x; C[4 * q + 1] = v.y; C[4 * q + 2] = v.z; C[4 * q + 3] = v.w;
    }
    const float rad = X[((size_t)b * T_ + t) * 4];

    float Cc[24];
#pragma unroll
    for (int c = 0; c < 24; ++c) Cc[c] = 0.f;

    for (int r = 0; r < 24; ++r) {
        float z[24];
#pragma unroll
        for (int c = 0; c < 24; ++c) {
            const float* w = Wr + (r * 24 + c) * 29;
            float zz = fmaf(w[25], rad, br[r * 24 + c]);
#pragma unroll
            for (int k = 0; k < 24; ++k) zz = fmaf(w[k], C[k], zz);
            z[c] = zz;
        }
        float m = z[0];
#pragma unroll
        for (int c = 1; c < 24; ++c) m = fmaxf(m, z[c]);
        float ss = 0.f;
#pragma unroll
        for (int c = 0; c < 24; ++c) { z[c] = __expf(z[c] - m); ss += z[c]; }
        const float fac = __fdividef(Cp[r], ss);
#pragma unroll
        for (int c = 0; c < 24; ++c) Cc[c] = fmaf(z[c], fac, Cc[c]);
    }

    float* cv = Cconv + (size_t)tid * CD_;
#pragma unroll
    for (int q = 0; q < 6; ++q) {
        float4 v;
        v.x = Cc[4 * q + 0]; v.y = Cc[4 * q + 1]; v.z = Cc[4 * q + 2]; v.w = Cc[4 * q + 3];
        *(float4*)(cv + 4 * q) = v;
    }

    float pai = 0.f;
#pragma unroll
    for (int c = 0; c < 24; ++c) pai += fabsf(C[c] * c2a[c]);
    float lea = 0.f, ste = 0.f, gra = 0.f, yie = 0.f;
#pragma unroll
    for (int c = 0; c < 8; ++c) lea += C[c];
#pragma unroll
    for (int c = 8; c < 16; ++c) ste += C[c];
#pragma unroll
    for (int c = 16; c < 24; ++c) { gra += C[c]; yie += fabsf(C[c] * g2y[c - 16]); }
    lea /= 0.419f; ste /= 0.431f; gra /= 0.487f; yie /= 0.487f;
    const float agb = lea + ste + gra;

    float* ad = allday + ((size_t)b * T_ + (t + 1)) * 7;
    ad[0] = ORY[((size_t)b * T_ + (t + 1)) * 7];
    ad[1] = pai; ad[2] = lea; ad[3] = ste; ad[4] = gra; ad[5] = agb; ad[6] = yie;
}

extern "C" void kernel_launch(void* const* d_in, const int* in_sizes, int n_in,
                              void* d_out, int out_size, void* d_ws, size_t ws_size,
                              hipStream_t stream) {
    const float* X   = (const float*)d_in[0];
    const float* ORY = (const float*)d_in[1];
    const float* Wr  = (const float*)d_in[2];
    const float* br  = (const float*)d_in[3];
    const float* Wp  = (const float*)d_in[4];
    const float* bp  = (const float*)d_in[5];
    const float* Wc  = (const float*)d_in[6];
    const float* bc  = (const float*)d_in[7];
    const float* Wa  = (const float*)d_in[8];
    const float* ba  = (const float*)d_in[9];
    const float* c2a = (const float*)d_in[10];
    const float* g2y = (const float*)d_in[11];

    float* allday = (float*)d_out;
    float* Ccell  = allday + (size_t)B_ * T_ * 7;
    float* Cconv  = Ccell + (size_t)B_ * NS_ * CD_;

    hipLaunchKernelGGL(mclstm_phase1, dim3(B_), dim3(256), 0, stream,
                       X, ORY, Wr, br, Wp, bp, Wc, bc, Wa, ba, Ccell);
    hipLaunchKernelGGL(mclstm_phase2, dim3(NTASK / 256), dim3(256), 0, stream,
                       X, ORY, Wr, br, c2a, g2y, Ccell, allday, Cconv);
}